// Round 10
// baseline (471.841 us; speedup 1.0000x reference)
//
#include <hip/hip_runtime.h>

// Problem: B=16, Q=1024, K=2048, D=1024, fp32.
// out = [context (B*Q*D) | attn (B*Q*K)] fp32, concatenated flat.
//
// Fast path (needs 320 MB d_ws): split-bf16 MFMA GEMM1 (hh+hl+lh via virtual-K),
// fp32 softmax (+bf16 copy), plain-bf16 MFMA GEMM2 on pre-transposed enc.
// GEMMs: m201-style 8-phase schedule. 256x256 tile, BK=64, 8 waves (2Mx4N),
// 2x64KiB LDS dbuf. Stage rotation derived from slot-death times (A halves die
// after ph3/ph7, B halves after ph2/ph6): ph1 d1.A1 | ph2 d0.B0 | ph3 d0.B1 |
// ph4 d0.A0 +VMC(6) | ph5 d0.A1 | ph6 d1.B0 | ph7 d1.B1 | ph8 d1.A0 +VMC(6).
// FIFO-audited: each VMC(6) completes exactly through the stages the next
// half-iteration reads; steady-state carry = 6 outstanding loads.

typedef __attribute__((ext_vector_type(8))) short s8v;       // 8 bf16 = 4 VGPR
typedef __attribute__((ext_vector_type(4))) float f32x4;     // MFMA acc
typedef __attribute__((ext_vector_type(8))) unsigned short us8;
typedef __attribute__((ext_vector_type(4))) unsigned short us4;

__device__ inline unsigned short f2bf(float f) {   // RNE
    unsigned u = __builtin_bit_cast(unsigned, f);
    u += 0x7FFFu + ((u >> 16) & 1u);
    return (unsigned short)(u >> 16);
}
__device__ inline float bf2f(unsigned short h) {
    return __builtin_bit_cast(float, (unsigned)h << 16);
}

__device__ __forceinline__ s8v lds_read128(unsigned addr) {
    s8v d;
    asm volatile("ds_read_b128 %0, %1" : "=v"(d) : "v"(addr));
    return d;
}
__device__ __forceinline__ void gld16(const unsigned short* src, unsigned short* dstLds) {
    __builtin_amdgcn_global_load_lds(
        (const __attribute__((address_space(1))) void*)src,
        (__attribute__((address_space(3))) void*)dstLds, 16, 0, 0);
}

#define LGKM(n)  asm volatile("s_waitcnt lgkmcnt(" #n ")" ::: "memory")
#define VMC(n)   asm volatile("s_waitcnt vmcnt(" #n ")" ::: "memory")
#define SB0      __builtin_amdgcn_sched_barrier(0)
#define BARR     __builtin_amdgcn_s_barrier()

// 16 MFMAs of one C-quadrant (4m x 2n x 2k), kf-outer for dep distance 8.
template<int MH, int NH>
__device__ __forceinline__ void mfma16(f32x4 (&acc)[8][4], const s8v (&a)[8], const s8v (&b)[4])
{
    __builtin_amdgcn_s_setprio(1);
    #pragma unroll
    for (int kf = 0; kf < 2; ++kf)
        #pragma unroll
        for (int mp = 0; mp < 4; ++mp)
            #pragma unroll
            for (int np = 0; np < 2; ++np)
                acc[MH * 4 + mp][NH * 2 + np] = __builtin_amdgcn_mfma_f32_16x16x32_bf16(
                    a[mp * 2 + kf], b[np * 2 + kf], acc[MH * 4 + mp][NH * 2 + np], 0, 0, 0);
    __builtin_amdgcn_s_setprio(0);
}

// 8 A-fragment reads for one mh half (4m x 2k), dbuf D.
template<int D, int MH>
__device__ __forceinline__ void readA(s8v (&a)[8], unsigned abase, unsigned cb0, unsigned cb1)
{
    const unsigned base = abase + D * 65536u + MH * 8192u;
    #pragma unroll
    for (int mp = 0; mp < 4; ++mp) {
        a[mp * 2 + 0] = lds_read128(base + mp * 2048u + cb0);
        a[mp * 2 + 1] = lds_read128(base + mp * 2048u + cb1);
    }
}
// 4 B-fragment reads for one nh pair (2n x 2k), dbuf D.
template<int D, int NH>
__device__ __forceinline__ void readB(s8v (&b)[4], unsigned bbase, unsigned cb0, unsigned cb1)
{
    const unsigned base = bbase + D * 65536u + NH * 4096u;
    #pragma unroll
    for (int np = 0; np < 2; ++np) {
        b[np * 2 + 0] = lds_read128(base + np * 2048u + cb0);
        b[np * 2 + 1] = lds_read128(base + np * 2048u + cb1);
    }
}

// ---------------- fp32 -> (bf16 hi, bf16 lo) split (dec) ----------------
__global__ __launch_bounds__(256)
void split_convert(const float* __restrict__ x, unsigned short* __restrict__ hi,
                   unsigned short* __restrict__ lo, int n4)
{
    int i = blockIdx.x * 256 + threadIdx.x;
    const int stride = gridDim.x * 256;
    for (; i < n4; i += stride) {
        const float4 v = reinterpret_cast<const float4*>(x)[i];
        us4 h, l;
        h.x = f2bf(v.x); l.x = f2bf(v.x - bf2f(h.x));
        h.y = f2bf(v.y); l.y = f2bf(v.y - bf2f(h.y));
        h.z = f2bf(v.z); l.z = f2bf(v.z - bf2f(h.z));
        h.w = f2bf(v.w); l.w = f2bf(v.w - bf2f(h.w));
        reinterpret_cast<us4*>(hi)[i] = h;
        reinterpret_cast<us4*>(lo)[i] = l;
    }
}

// ------- fused enc: fp32 -> (encH, encL) row-major + encT = encH transposed -------
__global__ __launch_bounds__(256)
void split_convert_enc(const float* __restrict__ enc,
                       unsigned short* __restrict__ encH,
                       unsigned short* __restrict__ encL,
                       unsigned short* __restrict__ encT)
{
    __shared__ unsigned short S[64][72];
    const int b  = blockIdx.z;
    const int kt = blockIdx.x;
    const int dt = blockIdx.y;
    const int tid = threadIdx.x;

    const int r   = tid >> 2;
    const int c16 = (tid & 3) * 16;

    const size_t inoff = (size_t)b * 2048 * 1024 + (size_t)(kt * 64 + r) * 1024 + dt * 64 + c16;
    const float4* src = reinterpret_cast<const float4*>(enc + inoff);

    us8 h0, h1, l0, l1;
    #pragma unroll
    for (int q = 0; q < 2; ++q) {
        const float4 a = src[q * 2 + 0];
        const float4 c = src[q * 2 + 1];
        us8& h = q ? h1 : h0;
        us8& l = q ? l1 : l0;
        h[0] = f2bf(a.x); l[0] = f2bf(a.x - bf2f(h[0]));
        h[1] = f2bf(a.y); l[1] = f2bf(a.y - bf2f(h[1]));
        h[2] = f2bf(a.z); l[2] = f2bf(a.z - bf2f(h[2]));
        h[3] = f2bf(a.w); l[3] = f2bf(a.w - bf2f(h[3]));
        h[4] = f2bf(c.x); l[4] = f2bf(c.x - bf2f(h[4]));
        h[5] = f2bf(c.y); l[5] = f2bf(c.y - bf2f(h[5]));
        h[6] = f2bf(c.z); l[6] = f2bf(c.z - bf2f(h[6]));
        h[7] = f2bf(c.w); l[7] = f2bf(c.w - bf2f(h[7]));
    }
    *reinterpret_cast<us8*>(&encH[inoff])     = h0;
    *reinterpret_cast<us8*>(&encH[inoff + 8]) = h1;
    *reinterpret_cast<us8*>(&encL[inoff])     = l0;
    *reinterpret_cast<us8*>(&encL[inoff + 8]) = l1;
    *reinterpret_cast<us8*>(&S[r][c16])     = h0;
    *reinterpret_cast<us8*>(&S[r][c16 + 8]) = h1;
    __syncthreads();

    const int d   = tid >> 2;
    const int k16 = (tid & 3) * 16;
    us8 w0, w1;
    #pragma unroll
    for (int j = 0; j < 8; ++j) { w0[j] = S[k16 + j][d]; w1[j] = S[k16 + 8 + j][d]; }
    const size_t outoff = (size_t)b * 1024 * 2048 + (size_t)(dt * 64 + d) * 2048 + kt * 64 + k16;
    *reinterpret_cast<us8*>(&encT[outoff])     = w0;
    *reinterpret_cast<us8*>(&encT[outoff + 8]) = w1;
}

// ---------------- 8-phase 256x256 NT MFMA GEMM (m201 port, fixed rotation) ----------------
// Out[m][n] = sum over NPASS passes: A_p[m][k]*B_p[n][k], k in [0, KSP*64)
template<int NPASS, int KSP, int NXT, int NYT>
__global__ __launch_bounds__(512, 2)
void gemm_nt_8ph(const unsigned short* __restrict__ A0p,
                 const unsigned short* __restrict__ A1p,
                 const unsigned short* __restrict__ A2p,
                 const unsigned short* __restrict__ B0p,
                 const unsigned short* __restrict__ B1p,
                 const unsigned short* __restrict__ B2p,
                 float* __restrict__ Out,
                 const int ldA, const int ldB, const int ldO,
                 const long long sA, const long long sB, const long long sO)
{
    constexpr int NK    = NPASS * KSP;     // total K-steps of 64 (even)
    constexpr int NITER = NK / 2;
    extern __shared__ unsigned short smem[];   // 2 dbuf x (A0,A1,B0,B1 halves 16KB) = 128 KiB

    // bijective XCD swizzle (nwg % 8 == 0 for both instantiations)
    int flat = blockIdx.x + NXT * (blockIdx.y + NYT * (int)blockIdx.z);
    const int nwg = NXT * NYT * (int)gridDim.z;
    flat = (flat & 7) * (nwg >> 3) + (flat >> 3);
    const int nt = flat % NXT;
    const int mt = (flat / NXT) % NYT;
    const int b  = flat / (NXT * NYT);

    const int tid = threadIdx.x, lane = tid & 63, wid = tid >> 6;
    const int wm = wid >> 2, wn = wid & 3;         // wave output: 128 x 64
    const int fr = lane & 15, kc = lane >> 4;

    const size_t arow = (size_t)b * sA + (size_t)(mt * 256) * ldA;
    const size_t brow = (size_t)b * sB + (size_t)(nt * 256) * ldB;
    const unsigned short* Ap0 = A0p + arow;
    const unsigned short* Ap1 = A1p + arow;
    const unsigned short* Ap2 = A2p + arow;
    const unsigned short* Bp0 = B0p + brow;
    const unsigned short* Bp1 = B1p + brow;
    const unsigned short* Bp2 = B2p + brow;

    // ---- staging offsets: LDS chunk -> swizzled global source ----
    // half-tile = [128 rows][64 k] bf16 (128B rows, 8 x 16B chunks); chunk c ^= row&7
    const int srow = tid >> 3;                       // 0..63 (second gload: +64)
    const int sc   = ((tid & 7) ^ (srow & 7)) * 8;   // element offset in row
    const int offA0 = srow * ldA + sc, offA1 = offA0 + 64 * ldA;
    const int offB0 = srow * ldB + sc, offB1 = offB0 + 64 * ldB;

    auto STAGEA = [&](int ks, int h) {
        const int p = ks / KSP;
        const unsigned short* s = ((p == 0) ? Ap0 : (p == 1) ? Ap1 : Ap2)
                                  + (size_t)(h * 128) * ldA + (ks - p * KSP) * 64;
        unsigned short* d = smem + ((ks & 1) * 32768 + h * 8192) + wid * 512;
        gld16(s + offA0, d);
        gld16(s + offA1, d + 4096);
    };
    auto STAGEB = [&](int ks, int h) {
        const int p = ks / KSP;
        const unsigned short* s = ((p == 0) ? Bp0 : (p == 1) ? Bp1 : Bp2)
                                  + (size_t)(h * 128) * ldB + (ks - p * KSP) * 64;
        unsigned short* d = smem + ((ks & 1) * 32768 + 16384 + h * 8192) + wid * 512;
        gld16(s + offB0, d);
        gld16(s + offB1, d + 4096);
    };

    // ---- fragment read bases (bytes) ----
    const unsigned lds0 =
        (unsigned)(uintptr_t)(__attribute__((address_space(3))) unsigned short*)smem;
    const unsigned cb0 = (unsigned)((kc ^ (fr & 7)) * 16);
    const unsigned cb1 = cb0 ^ 64u;
    const unsigned abase = lds0 + wm * 16384u + fr * 128u;
    const unsigned bbase = lds0 + 32768u + (wn >> 1) * 16384u + (wn & 1) * 8192u + fr * 128u;

    f32x4 acc[8][4];
    #pragma unroll
    for (int m = 0; m < 8; ++m)
        #pragma unroll
        for (int n = 0; n < 4; ++n) acc[m][n] = (f32x4){0.f, 0.f, 0.f, 0.f};

    s8v a[8], b0[4], b1[4];

    // ---- prologue: d0 <- ks0 (4 halves, 8 loads); d1 <- ks1 {B0,B1,A0} (6 loads) ----
    STAGEA(0, 0); STAGEA(0, 1); STAGEB(0, 0); STAGEB(0, 1);
    STAGEB(1, 0); STAGEB(1, 1); STAGEA(1, 0);
    VMC(6);                       // d0 complete; d1's 6 in flight (steady-state carry)
    BARR;

    auto iter = [&](const int t, const bool last) {
        const int ks0 = 2 * t;
        // ph1: reads A(d0,mh0)+B0(d0) [12]; stage d1.A1 <- ks0+1 (always needed)
        readA<0, 0>(a, abase, cb0, cb1);
        readB<0, 0>(b0, bbase, cb0, cb1);
        STAGEA(ks0 + 1, 1);
        LGKM(8); SB0; BARR; LGKM(0); SB0;
        mfma16<0, 0>(acc, a, b0);
        BARR;
        // ph2: reads B1(d0) [4]; stage d0.B0 <- ks0+2 (B0 slot dead after ph... reads done ph1? B0 read ph1 only -> dead, but
        //      conservative: slot d0.B0's reads were issued ph1 and completed at each wave's LGKM(0) before ph1 MFMA; barrier passed)
        readB<0, 1>(b1, bbase, cb0, cb1);
        if (!last) STAGEB(ks0 + 2, 0);
        SB0; BARR; LGKM(0); SB0;
        mfma16<0, 1>(acc, a, b1);
        BARR;
        // ph3: reads A(d0,mh1) [8]; stage d0.B1 <- ks0+2 (B1 dead after ph2)
        readA<0, 1>(a, abase, cb0, cb1);
        if (!last) STAGEB(ks0 + 2, 1);
        LGKM(4); SB0; BARR; LGKM(0); SB0;
        mfma16<1, 0>(acc, a, b0);
        BARR;
        // ph4: stage d0.A0 <- ks0+2 (A halves dead after ph3); GATE
        if (!last) STAGEA(ks0 + 2, 0);
        if (last) { VMC(0); } else { VMC(6); }   // completes through ph1's d1.A1
        SB0; BARR;
        mfma16<1, 1>(acc, a, b1);
        BARR;
        // ph5: reads A(d1,mh0)+B0(d1) [12]; stage d0.A1 <- ks0+2
        readA<1, 0>(a, abase, cb0, cb1);
        readB<1, 0>(b0, bbase, cb0, cb1);
        if (!last) STAGEA(ks0 + 2, 1);
        LGKM(8); SB0; BARR; LGKM(0); SB0;
        mfma16<0, 0>(acc, a, b0);
        BARR;
        // ph6: reads B1(d1) [4]; stage d1.B0 <- ks0+3 (dead after ph5)
        readB<1, 1>(b1, bbase, cb0, cb1);
        if (!last) STAGEB(ks0 + 3, 0);
        SB0; BARR; LGKM(0); SB0;
        mfma16<0, 1>(acc, a, b1);
        BARR;
        // ph7: reads A(d1,mh1) [8]; stage d1.B1 <- ks0+3 (dead after ph6)
        readA<1, 1>(a, abase, cb0, cb1);
        if (!last) STAGEB(ks0 + 3, 1);
        LGKM(4); SB0; BARR; LGKM(0); SB0;
        mfma16<1, 0>(acc, a, b0);
        BARR;
        // ph8: stage d1.A0 <- ks0+3 (A dead after ph7); GATE
        if (!last) STAGEA(ks0 + 3, 0);
        if (last) { VMC(0); } else { VMC(6); }   // completes through ph5's d0.A1
        SB0; BARR;
        mfma16<1, 1>(acc, a, b1);
        BARR;
    };

    for (int t = 0; t < NITER - 1; ++t) iter(t, false);
    iter(NITER - 1, true);

    // C/D: col = lane&15, row = (lane>>4)*4 + reg   [m89-verified]
    float* Ob = Out + (size_t)b * sO + (size_t)(mt * 256 + wm * 128) * ldO + nt * 256 + wn * 64;
    const int cr = (lane >> 4) << 2;
    const int cc = lane & 15;
    #pragma unroll
    for (int m = 0; m < 8; ++m)
        #pragma unroll
        for (int n = 0; n < 4; ++n)
            #pragma unroll
            for (int r = 0; r < 4; ++r)
                Ob[(size_t)(m * 16 + cr + r) * ldO + n * 16 + cc] = acc[m][n][r];
}

// ---------------- softmax (fp32 in-place + bf16 copy) ----------------
__global__ __launch_bounds__(256)
void softmax_rows_bf(float* __restrict__ P, unsigned short* __restrict__ Pb)
{
    float* p = P + (size_t)blockIdx.x * 2048;
    unsigned short* pb = Pb + (size_t)blockIdx.x * 2048;
    const int tid = threadIdx.x;

    float4 v0 = *reinterpret_cast<const float4*>(&p[tid * 4]);
    float4 v1 = *reinterpret_cast<const float4*>(&p[1024 + tid * 4]);

    float m = fmaxf(fmaxf(fmaxf(v0.x, v0.y), fmaxf(v0.z, v0.w)),
                    fmaxf(fmaxf(v1.x, v1.y), fmaxf(v1.z, v1.w)));
    #pragma unroll
    for (int off = 32; off; off >>= 1) m = fmaxf(m, __shfl_xor(m, off));

    __shared__ float red[8];
    const int wid = tid >> 6;
    if ((tid & 63) == 0) red[wid] = m;
    __syncthreads();
    m = fmaxf(fmaxf(red[0], red[1]), fmaxf(red[2], red[3]));

    v0.x = __expf(v0.x - m); v0.y = __expf(v0.y - m);
    v0.z = __expf(v0.z - m); v0.w = __expf(v0.w - m);
    v1.x = __expf(v1.x - m); v1.y = __expf(v1.y - m);
    v1.z = __expf(v1.z - m); v1.w = __expf(v1.w - m);

    float s = ((v0.x + v0.y) + (v0.z + v0.w)) + ((v1.x + v1.y) + (v1.z + v1.w));
    #pragma unroll
    for (int off = 32; off; off >>= 1) s += __shfl_xor(s, off);
    if ((tid & 63) == 0) red[4 + wid] = s;
    __syncthreads();
    const float inv = 1.0f / ((red[4] + red[5]) + (red[6] + red[7]));

    v0.x *= inv; v0.y *= inv; v0.z *= inv; v0.w *= inv;
    v1.x *= inv; v1.y *= inv; v1.z *= inv; v1.w *= inv;
    *reinterpret_cast<float4*>(&p[tid * 4]) = v0;
    *reinterpret_cast<float4*>(&p[1024 + tid * 4]) = v1;

    us4 h0, h1;
    h0.x = f2bf(v0.x); h0.y = f2bf(v0.y); h0.z = f2bf(v0.z); h0.w = f2bf(v0.w);
    h1.x = f2bf(v1.x); h1.y = f2bf(v1.y); h1.z = f2bf(v1.z); h1.w = f2bf(v1.w);
    *reinterpret_cast<us4*>(&pb[tid * 4]) = h0;
    *reinterpret_cast<us4*>(&pb[1024 + tid * 4]) = h1;
}

// ======================= fp32 fallback path =======================
#define BM 128
#define BN 128
#define BK 32
#define LDT 132

template <bool TRANSB>
__global__ __launch_bounds__(256, 2)
void gemm_tile(const float* __restrict__ X, const float* __restrict__ Y,
               float* __restrict__ Out,
               int ldX, int ldY, int ldO, int KD,
               long long strideX, long long strideY, long long strideO)
{
    __shared__ float As[BK][LDT];
    __shared__ float Bs[BK][LDT];
    const int b  = blockIdx.z;
    const int mt = blockIdx.y;
    const int nt = blockIdx.x;
    const float* Xb = X + (size_t)b * strideX + (size_t)mt * BM * ldX;
    const float* Yb = TRANSB ? (Y + (size_t)b * strideY + (size_t)nt * BN * ldY)
                             : (Y + (size_t)b * strideY + (size_t)nt * BN);
    float* Ob = Out + (size_t)b * strideO + (size_t)mt * BM * ldO + (size_t)nt * BN;
    const int tid = threadIdx.x;
    const int tx = tid & 15;
    const int ty = tid >> 4;
    const int sr = tid >> 3;
    const int sc = (tid & 7) << 2;
    const int br = tid >> 5;
    const int bc = (tid & 31) << 2;
    float acc[8][8];
    #pragma unroll
    for (int i = 0; i < 8; ++i)
        #pragma unroll
        for (int j = 0; j < 8; ++j) acc[i][j] = 0.f;
    for (int k0 = 0; k0 < KD; k0 += BK) {
        #pragma unroll
        for (int p = 0; p < 4; ++p) {
            const float4 v = *reinterpret_cast<const float4*>(
                &Xb[(size_t)(sr + 32 * p) * ldX + k0 + sc]);
            As[sc + 0][sr + 32 * p] = v.x;
            As[sc + 1][sr + 32 * p] = v.y;
            As[sc + 2][sr + 32 * p] = v.z;
            As[sc + 3][sr + 32 * p] = v.w;
        }
        if (TRANSB) {
            #pragma unroll
            for (int p = 0; p < 4; ++p) {
                const float4 v = *reinterpret_cast<const float4*>(
                    &Yb[(size_t)(sr + 32 * p) * ldY + k0 + sc]);
                Bs[sc + 0][sr + 32 * p] = v.x;
                Bs[sc + 1][sr + 32 * p] = v.y;
                Bs[sc + 2][sr + 32 * p] = v.z;
                Bs[sc + 3][sr + 32 * p] = v.w;
            }
        } else {
            #pragma unroll
            for (int p = 0; p < 4; ++p) {
                const float4 v = *reinterpret_cast<const float4*>(
                    &Yb[(size_t)(k0 + br + 8 * p) * ldY + bc]);
                *reinterpret_cast<float4*>(&Bs[br + 8 * p][bc]) = v;
            }
        }
        __syncthreads();
        #pragma unroll 8
        for (int kk = 0; kk < BK; ++kk) {
            const float4 a0 = *reinterpret_cast<const float4*>(&As[kk][ty * 4]);
            const float4 a1 = *reinterpret_cast<const float4*>(&As[kk][64 + ty * 4]);
            const float4 b0 = *reinterpret_cast<const float4*>(&Bs[kk][tx * 4]);
            const float4 b1 = *reinterpret_cast<const float4*>(&Bs[kk][64 + tx * 4]);
            const float av[8] = {a0.x, a0.y, a0.z, a0.w, a1.x, a1.y, a1.z, a1.w};
            const float bv[8] = {b0.x, b0.y, b0.z, b0.w, b1.x, b1.y, b1.z, b1.w};
            #pragma unroll
            for (int i = 0; i < 8; ++i)
                #pragma unroll
                for (int j = 0; j < 8; ++j)
                    acc[i][j] = fmaf(av[i], bv[j], acc[i][j]);
        }
        __syncthreads();
    }
    #pragma unroll
    for (int i = 0; i < 8; ++i) {
        const int r = (i < 4) ? (ty * 4 + i) : (64 + ty * 4 + (i - 4));
        const float4 w0 = make_float4(acc[i][0], acc[i][1], acc[i][2], acc[i][3]);
        const float4 w1 = make_float4(acc[i][4], acc[i][5], acc[i][6], acc[i][7]);
        *reinterpret_cast<float4*>(&Ob[(size_t)r * ldO + tx * 4])      = w0;
        *reinterpret_cast<float4*>(&Ob[(size_t)r * ldO + 64 + tx * 4]) = w1;
    }
}

__global__ __launch_bounds__(256)
void softmax_rows(float* __restrict__ P)
{
    float* p = P + (size_t)blockIdx.x * 2048;
    const int tid = threadIdx.x;
    float4 v0 = *reinterpret_cast<const float4*>(&p[tid * 4]);
    float4 v1 = *reinterpret_cast<const float4*>(&p[1024 + tid * 4]);
    float m = fmaxf(fmaxf(fmaxf(v0.x, v0.y), fmaxf(v0.z, v0.w)),
                    fmaxf(fmaxf(v1.x, v1.y), fmaxf(v1.z, v1.w)));
    #pragma unroll
    for (int off = 32; off; off >>= 1) m = fmaxf(m, __shfl_xor(m, off));
    __shared__ float red[8];
    const int wid = tid >> 6;
    if ((tid & 63) == 0) red[wid] = m;
    __syncthreads();
    m = fmaxf(fmaxf(red[0], red[1]), fmaxf(red[2], red[3]));
    v0.x = __expf(v0.x - m); v0.y = __expf(v0.y - m);
    v0.z = __expf(v0.z - m); v0.w = __expf(v0.w - m);
    v1.x = __expf(v1.x - m); v1.y = __expf(v1.y - m);
    v1.z = __expf(v1.z - m); v1.w = __expf(v1.w - m);
    float s = ((v0.x + v0.y) + (v0.z + v0.w)) + ((v1.x + v1.y) + (v1.z + v1.w));
    #pragma unroll
    for (int off = 32; off; off >>= 1) s += __shfl_xor(s, off);
    if ((tid & 63) == 0) red[4 + wid] = s;
    __syncthreads();
    const float inv = 1.0f / ((red[4] + red[5]) + (red[6] + red[7]));
    v0.x *= inv; v0.y *= inv; v0.z *= inv; v0.w *= inv;
    v1.x *= inv; v1.y *= inv; v1.z *= inv; v1.w *= inv;
    *reinterpret_cast<float4*>(&p[tid * 4]) = v0;
    *reinterpret_cast<float4*>(&p[1024 + tid * 4]) = v1;
}

// =========================== launcher ===========================
extern "C" void kernel_launch(void* const* d_in, const int* in_sizes, int n_in,
                              void* d_out, int out_size, void* d_ws, size_t ws_size,
                              hipStream_t stream)
{
    const float* dec = (const float*)d_in[0];   // [16,1024,1024]
    const float* enc = (const float*)d_in[1];   // [16,2048,1024]
    float* ctx  = (float*)d_out;                        // [16,1024,1024]
    float* attn = ctx + (size_t)16 * 1024 * 1024;       // [16,1024,2048]

    const long long DECN = 16LL * 1024 * 1024;
    const long long ENCN = 16LL * 2048 * 1024;
    const size_t NEED = (size_t)(2 * DECN + 4 * ENCN) * 2;  // 320 MB

    if (ws_size >= NEED) {
        unsigned short* decH  = (unsigned short*)d_ws;
        unsigned short* decL  = decH + DECN;
        unsigned short* encH  = decL + DECN;
        unsigned short* encL  = encH + ENCN;
        unsigned short* encT  = encL + ENCN;   // [16][1024][2048]
        unsigned short* attnB = encT + ENCN;   // [16][1024][2048]

        hipFuncSetAttribute((const void*)&gemm_nt_8ph<3, 16, 8, 4>,
                            hipFuncAttributeMaxDynamicSharedMemorySize, 131072);
        hipFuncSetAttribute((const void*)&gemm_nt_8ph<1, 32, 4, 4>,
                            hipFuncAttributeMaxDynamicSharedMemorySize, 131072);

        split_convert<<<2048, 256, 0, stream>>>(dec, decH, decL, (int)(DECN / 4));
        split_convert_enc<<<dim3(32, 16, 16), 256, 0, stream>>>(enc, encH, encL, encT);

        // scores = dec @ enc^T: passes {Ah*Bh, Ah*Bl, Al*Bh}, virtual K = 3*1024
        gemm_nt_8ph<3, 16, 8, 4><<<dim3(8, 4, 16), 512, 131072, stream>>>(
            decH, decH, decL, encH, encL, encH, attn,
            1024, 1024, 2048,
            1024LL * 1024, 2048LL * 1024, 1024LL * 2048);

        softmax_rows_bf<<<16 * 1024, 256, 0, stream>>>(attn, attnB);

        // context = attnB (NT) encT, K = 2048
        gemm_nt_8ph<1, 32, 4, 4><<<dim3(4, 4, 16), 512, 131072, stream>>>(
            attnB, attnB, attnB, encT, encT, encT, ctx,
            2048, 2048, 1024,
            1024LL * 2048, 1024LL * 2048, 1024LL * 1024);
    } else {
        gemm_tile<true><<<dim3(2048 / BN, 1024 / BM, 16), 256, 0, stream>>>(
            dec, enc, attn, 1024, 1024, 2048, 1024,
            1024LL * 1024, 2048LL * 1024, 1024LL * 2048);
        softmax_rows<<<dim3(16 * 1024), 256, 0, stream>>>(attn);
        gemm_tile<false><<<dim3(1024 / BN, 1024 / BM, 16), 256, 0, stream>>>(
            attn, enc, ctx, 2048, 1024, 1024, 2048,
            1024LL * 2048, 2048LL * 1024, 1024LL * 1024);
    }
}

// Round 11
// 411.380 us; speedup vs baseline: 1.1470x; 1.1470x over previous
//
#include <hip/hip_runtime.h>

// Problem: B=16, Q=1024, K=2048, D=1024, fp32.
// out = [context (B*Q*D) | attn (B*Q*K)] fp32, concatenated flat.
//
// Fast path (needs 320 MB d_ws): split-bf16 MFMA GEMM1 (hh+hl+lh), fp32 softmax
// (+bf16 copy), plain-bf16 MFMA GEMM2 on pre-transposed enc.
// GEMM1: QUAD-SET kernel — stage {Ah,Al,Bh,Bl} K-32 tiles ONCE (64KB set,
// ring-2), run all 3 MFMA passes per set: 24 ds_reads + 8 DMA serve 96 MFMA
// (vs 36 reads + 12 DMA before). GEMM2: r8 ring-4 kernel (measured ~70us).

typedef __attribute__((ext_vector_type(8))) short s8v;       // 8 bf16 = 4 VGPR
typedef __attribute__((ext_vector_type(4))) float f32x4;     // MFMA acc
typedef __attribute__((ext_vector_type(8))) unsigned short us8;
typedef __attribute__((ext_vector_type(4))) unsigned short us4;

__device__ inline unsigned short f2bf(float f) {   // RNE
    unsigned u = __builtin_bit_cast(unsigned, f);
    u += 0x7FFFu + ((u >> 16) & 1u);
    return (unsigned short)(u >> 16);
}
__device__ inline float bf2f(unsigned short h) {
    return __builtin_bit_cast(float, (unsigned)h << 16);
}

__device__ __forceinline__ s8v lds_read128(unsigned addr) {
    s8v d;
    asm volatile("ds_read_b128 %0, %1" : "=v"(d) : "v"(addr));
    return d;
}
__device__ __forceinline__ void gld16(const unsigned short* src, unsigned short* dstLds) {
    __builtin_amdgcn_global_load_lds(
        (const __attribute__((address_space(1))) void*)src,
        (__attribute__((address_space(3))) void*)dstLds, 16, 0, 0);
}

#define LGKM0    asm volatile("s_waitcnt lgkmcnt(0)" ::: "memory")
#define VMC(n)   asm volatile("s_waitcnt vmcnt(" #n ")" ::: "memory")
#define SB0      __builtin_amdgcn_sched_barrier(0)
#define BARR     __builtin_amdgcn_s_barrier()

// ---------------- fp32 -> (bf16 hi, bf16 lo) split (dec) ----------------
__global__ __launch_bounds__(256)
void split_convert(const float* __restrict__ x, unsigned short* __restrict__ hi,
                   unsigned short* __restrict__ lo, int n4)
{
    int i = blockIdx.x * 256 + threadIdx.x;
    const int stride = gridDim.x * 256;
    for (; i < n4; i += stride) {
        const float4 v = reinterpret_cast<const float4*>(x)[i];
        us4 h, l;
        h.x = f2bf(v.x); l.x = f2bf(v.x - bf2f(h.x));
        h.y = f2bf(v.y); l.y = f2bf(v.y - bf2f(h.y));
        h.z = f2bf(v.z); l.z = f2bf(v.z - bf2f(h.z));
        h.w = f2bf(v.w); l.w = f2bf(v.w - bf2f(h.w));
        reinterpret_cast<us4*>(hi)[i] = h;
        reinterpret_cast<us4*>(lo)[i] = l;
    }
}

// ------- fused enc: fp32 -> (encH, encL) row-major + encT = encH transposed -------
__global__ __launch_bounds__(256)
void split_convert_enc(const float* __restrict__ enc,
                       unsigned short* __restrict__ encH,
                       unsigned short* __restrict__ encL,
                       unsigned short* __restrict__ encT)
{
    __shared__ unsigned short S[64][72];
    const int b  = blockIdx.z;
    const int kt = blockIdx.x;
    const int dt = blockIdx.y;
    const int tid = threadIdx.x;

    const int r   = tid >> 2;
    const int c16 = (tid & 3) * 16;

    const size_t inoff = (size_t)b * 2048 * 1024 + (size_t)(kt * 64 + r) * 1024 + dt * 64 + c16;
    const float4* src = reinterpret_cast<const float4*>(enc + inoff);

    us8 h0, h1, l0, l1;
    #pragma unroll
    for (int q = 0; q < 2; ++q) {
        const float4 a = src[q * 2 + 0];
        const float4 c = src[q * 2 + 1];
        us8& h = q ? h1 : h0;
        us8& l = q ? l1 : l0;
        h[0] = f2bf(a.x); l[0] = f2bf(a.x - bf2f(h[0]));
        h[1] = f2bf(a.y); l[1] = f2bf(a.y - bf2f(h[1]));
        h[2] = f2bf(a.z); l[2] = f2bf(a.z - bf2f(h[2]));
        h[3] = f2bf(a.w); l[3] = f2bf(a.w - bf2f(h[3]));
        h[4] = f2bf(c.x); l[4] = f2bf(c.x - bf2f(h[4]));
        h[5] = f2bf(c.y); l[5] = f2bf(c.y - bf2f(h[5]));
        h[6] = f2bf(c.z); l[6] = f2bf(c.z - bf2f(h[6]));
        h[7] = f2bf(c.w); l[7] = f2bf(c.w - bf2f(h[7]));
    }
    *reinterpret_cast<us8*>(&encH[inoff])     = h0;
    *reinterpret_cast<us8*>(&encH[inoff + 8]) = h1;
    *reinterpret_cast<us8*>(&encL[inoff])     = l0;
    *reinterpret_cast<us8*>(&encL[inoff + 8]) = l1;
    *reinterpret_cast<us8*>(&S[r][c16])     = h0;
    *reinterpret_cast<us8*>(&S[r][c16 + 8]) = h1;
    __syncthreads();

    const int d   = tid >> 2;
    const int k16 = (tid & 3) * 16;
    us8 w0, w1;
    #pragma unroll
    for (int j = 0; j < 8; ++j) { w0[j] = S[k16 + j][d]; w1[j] = S[k16 + 8 + j][d]; }
    const size_t outoff = (size_t)b * 1024 * 2048 + (size_t)(dt * 64 + d) * 2048 + kt * 64 + k16;
    *reinterpret_cast<us8*>(&encT[outoff])     = w0;
    *reinterpret_cast<us8*>(&encT[outoff + 8]) = w1;
}

// ---------------- GEMM1: quad-set split GEMM (hh + hl + lh) ----------------
// scores = A (M=256-tile) x {B} NT over K = KTILES*32; per K-32 tile stage
// {Ah,Al,Bh,Bl} once into a 64KB set (ring-2) and run 3 MFMA passes.
template<int KTILES, int NXT, int NYT>
__global__ __launch_bounds__(512, 2)
void gemm1_quad(const unsigned short* __restrict__ Ah_, const unsigned short* __restrict__ Al_,
                const unsigned short* __restrict__ Bh_, const unsigned short* __restrict__ Bl_,
                float* __restrict__ Out,
                const int ldA, const int ldB, const int ldO,
                const long long sA, const long long sB, const long long sO)
{
    extern __shared__ unsigned short smem[];   // 2 sets x [Ah|Al|Bh|Bl] x 16KB = 128 KiB

    // bijective XCD swizzle (nwg % 8 == 0)
    int flat = blockIdx.x + NXT * (blockIdx.y + NYT * (int)blockIdx.z);
    const int nwg = NXT * NYT * (int)gridDim.z;
    flat = (flat & 7) * (nwg >> 3) + (flat >> 3);
    const int nt = flat % NXT;
    const int mt = (flat / NXT) % NYT;
    const int b  = flat / (NXT * NYT);

    const int tid = threadIdx.x, lane = tid & 63, wid = tid >> 6;
    const int wm = wid >> 2, wn = wid & 3;         // wave tile: 128 x 64

    const size_t arow = (size_t)b * sA + (size_t)(mt * 256) * ldA;
    const size_t brow = (size_t)b * sB + (size_t)(nt * 256) * ldB;
    const unsigned short* Ahb = Ah_ + arow;
    const unsigned short* Alb = Al_ + arow;
    const unsigned short* Bhb = Bh_ + brow;
    const unsigned short* Blb = Bl_ + brow;

    // staging: linear LDS chunk ci -> swizzled global source (r6-verified mapping)
    // array = [256 rows][32 k] bf16; row = 64B = 4 x 16B chunks; chunk c ^= (r>>1)&3
    const int ci0 = tid, ci1 = 512 + tid;
    const int r0 = ci0 >> 2, r1 = ci1 >> 2;
    const int cs0 = ((ci0 & 3) ^ ((r0 >> 1) & 3)) * 8;
    const int cs1 = ((ci1 & 3) ^ ((r1 >> 1) & 3)) * 8;
    const int aoff0 = r0 * ldA + cs0, aoff1 = r1 * ldA + cs1;
    const int boff0 = r0 * ldB + cs0, boff1 = r1 * ldB + cs1;
    const int wd0 = wid * 512, wd1 = 4096 + wid * 512;   // elems within one array

    auto stage_set = [&](int t) {
        const int k0 = t * 32;
        unsigned short* s = smem + (t & 1) * 32768;       // 64KB set (elems)
        gld16(Ahb + k0 + aoff0, s + wd0);          gld16(Ahb + k0 + aoff1, s + wd1);
        gld16(Alb + k0 + aoff0, s + 8192 + wd0);   gld16(Alb + k0 + aoff1, s + 8192 + wd1);
        gld16(Bhb + k0 + boff0, s + 16384 + wd0);  gld16(Bhb + k0 + boff1, s + 16384 + wd1);
        gld16(Blb + k0 + boff0, s + 24576 + wd0);  gld16(Blb + k0 + boff1, s + 24576 + wd1);
    };

    // fragment read byte offsets within one 16KB array (swizzled)
    const int fr = lane & 15, kc = lane >> 4;
    unsigned offA[8], offB[4];
    #pragma unroll
    for (int m = 0; m < 8; ++m) {
        const int R = wm * 128 + m * 16 + fr;
        offA[m] = (unsigned)(R * 64) + ((unsigned)(kc ^ ((R >> 1) & 3)) << 4);
    }
    #pragma unroll
    for (int n = 0; n < 4; ++n) {
        const int R = wn * 64 + n * 16 + fr;
        offB[n] = (unsigned)(R * 64) + ((unsigned)(kc ^ ((R >> 1) & 3)) << 4);
    }

    const unsigned lds0 =
        (unsigned)(uintptr_t)(__attribute__((address_space(3))) unsigned short*)smem;

    f32x4 acc[8][4];
    #pragma unroll
    for (int m = 0; m < 8; ++m)
        #pragma unroll
        for (int n = 0; n < 4; ++n) acc[m][n] = (f32x4){0.f, 0.f, 0.f, 0.f};

    s8v ah[8], al[8], bh[4], bl[4];

    stage_set(0);
    VMC(0); BARR;

    for (int t = 0; t < KTILES; ++t) {
        const unsigned base = lds0 + (unsigned)(t & 1) * 65536u;
        const bool notlast = (t + 1 < KTILES);

        // ---- ph1: read Ah + Bh; stage next set ----
        #pragma unroll
        for (int n = 0; n < 4; ++n) bh[n] = lds_read128(base + 32768u + offB[n]);
        #pragma unroll
        for (int m = 0; m < 8; ++m) ah[m] = lds_read128(base + offA[m]);
        if (notlast) stage_set(t + 1);   // targets buf(t-1): reads done before last barrier
        BARR; LGKM0; SB0;
        __builtin_amdgcn_s_setprio(1);
        #pragma unroll
        for (int m = 0; m < 8; ++m)
            #pragma unroll
            for (int n = 0; n < 4; ++n)
                acc[m][n] = __builtin_amdgcn_mfma_f32_16x16x32_bf16(ah[m], bh[n], acc[m][n], 0, 0, 0);
        __builtin_amdgcn_s_setprio(0);
        BARR;

        // ---- ph2: read Bl; MFMA Ah x Bl ----
        #pragma unroll
        for (int n = 0; n < 4; ++n) bl[n] = lds_read128(base + 49152u + offB[n]);
        BARR; LGKM0; SB0;
        __builtin_amdgcn_s_setprio(1);
        #pragma unroll
        for (int m = 0; m < 8; ++m)
            #pragma unroll
            for (int n = 0; n < 4; ++n)
                acc[m][n] = __builtin_amdgcn_mfma_f32_16x16x32_bf16(ah[m], bl[n], acc[m][n], 0, 0, 0);
        __builtin_amdgcn_s_setprio(0);
        BARR;

        // ---- ph3: read Al; MFMA Al x Bh; gate next set ----
        #pragma unroll
        for (int m = 0; m < 8; ++m) al[m] = lds_read128(base + 16384u + offA[m]);
        BARR; LGKM0; SB0;
        __builtin_amdgcn_s_setprio(1);
        #pragma unroll
        for (int m = 0; m < 8; ++m)
            #pragma unroll
            for (int n = 0; n < 4; ++n)
                acc[m][n] = __builtin_amdgcn_mfma_f32_16x16x32_bf16(al[m], bh[n], acc[m][n], 0, 0, 0);
        __builtin_amdgcn_s_setprio(0);
        if (notlast) VMC(0);             // next set landed (issued ~2 phases ago)
        BARR;
    }

    // C/D: col = lane&15, row = (lane>>4)*4 + reg   [m89-verified]
    float* Ob = Out + (size_t)b * sO + (size_t)(mt * 256 + wm * 128) * ldO + nt * 256 + wn * 64;
    const int cr = (lane >> 4) << 2;
    const int cc = lane & 15;
    #pragma unroll
    for (int m = 0; m < 8; ++m)
        #pragma unroll
        for (int n = 0; n < 4; ++n)
            #pragma unroll
            for (int r = 0; r < 4; ++r)
                Ob[(size_t)(m * 16 + cr + r) * ldO + n * 16 + cc] = acc[m][n][r];
}

// ---------------- GEMM2: r8 ring-4 kernel (verbatim, NPASS=1 use) ----------------
template<int NPASS, int KPP, int NXT, int NYT>
__global__ __launch_bounds__(512, 2)
void gemm_nt_256(const unsigned short* __restrict__ A0,
                 const unsigned short* __restrict__ A1,
                 const unsigned short* __restrict__ A2,
                 const unsigned short* __restrict__ B0,
                 const unsigned short* __restrict__ B1,
                 const unsigned short* __restrict__ B2,
                 float* __restrict__ Out,
                 const int ldA, const int ldB, const int ldO,
                 const long long sA, const long long sB, const long long sO)
{
    constexpr int TPP = KPP / 32;
    constexpr int NT  = NPASS * TPP;
    extern __shared__ unsigned short smem[];

    int flat = blockIdx.x + NXT * (blockIdx.y + NYT * (int)blockIdx.z);
    const int nwg = NXT * NYT * (int)gridDim.z;
    flat = (flat & 7) * (nwg >> 3) + (flat >> 3);
    const int nt = flat % NXT;
    const int mt = (flat / NXT) % NYT;
    const int b  = flat / (NXT * NYT);

    const int tid = threadIdx.x, lane = tid & 63, wid = tid >> 6;
    const int wm = wid >> 2, wn = wid & 3;

    const size_t arow = (size_t)b * sA + (size_t)(mt * 256) * ldA;
    const size_t brow = (size_t)b * sB + (size_t)(nt * 256) * ldB;
    const unsigned short* Ap0 = A0 + arow;
    const unsigned short* Ap1 = A1 + arow;
    const unsigned short* Ap2 = A2 + arow;
    const unsigned short* Bp0 = B0 + brow;
    const unsigned short* Bp1 = B1 + brow;
    const unsigned short* Bp2 = B2 + brow;

    const int ci0 = tid, ci1 = 512 + tid;
    const int r0 = ci0 >> 2, r1 = ci1 >> 2;
    const int cs0 = ((ci0 & 3) ^ ((r0 >> 1) & 3)) * 8;
    const int cs1 = ((ci1 & 3) ^ ((r1 >> 1) & 3)) * 8;
    const int aoff0 = r0 * ldA + cs0, aoff1 = r1 * ldA + cs1;
    const int boff0 = r0 * ldB + cs0, boff1 = r1 * ldB + cs1;
    const int wd0 = wid * 512;
    const int wd1 = 4096 + wid * 512;

    auto stageA = [&](int t) {
        const int p  = t / TPP;
        const int k0 = (t % TPP) * 32;
        const unsigned short* As = (p == 0) ? Ap0 : (p == 1 ? Ap1 : Ap2);
        unsigned short* d = smem + (t & 3) * 16384;
        gld16(As + k0 + aoff0, d + wd0);
        gld16(As + k0 + aoff1, d + wd1);
    };
    auto stageB = [&](int t) {
        const int p  = t / TPP;
        const int k0 = (t % TPP) * 32;
        const unsigned short* Bs = (p == 0) ? Bp0 : (p == 1 ? Bp1 : Bp2);
        unsigned short* d = smem + (t & 3) * 16384 + 8192;
        gld16(Bs + k0 + boff0, d + wd0);
        gld16(Bs + k0 + boff1, d + wd1);
    };

    const int fr = lane & 15;
    const int kc = lane >> 4;
    unsigned offA[8], offB[4];
    #pragma unroll
    for (int m = 0; m < 8; ++m) {
        const int R = wm * 128 + m * 16 + fr;
        offA[m] = (unsigned)(R * 64) + ((unsigned)(kc ^ ((R >> 1) & 3)) << 4);
    }
    #pragma unroll
    for (int n = 0; n < 4; ++n) {
        const int R = wn * 64 + n * 16 + fr;
        offB[n] = 16384u + (unsigned)(R * 64) + ((unsigned)(kc ^ ((R >> 1) & 3)) << 4);
    }

    const unsigned lds0 =
        (unsigned)(uintptr_t)(__attribute__((address_space(3))) unsigned short*)smem;

    f32x4 acc[8][4];
    #pragma unroll
    for (int m = 0; m < 8; ++m)
        #pragma unroll
        for (int n = 0; n < 4; ++n) acc[m][n] = (f32x4){0.f, 0.f, 0.f, 0.f};

    stageA(0); stageB(0); stageA(1); stageB(1); stageA(2); stageB(2);
    asm volatile("s_waitcnt vmcnt(4)" ::: "memory");
    __builtin_amdgcn_s_barrier();

    s8v fA[8], fB[4], gA[8], gB[4];
    #pragma unroll
    for (int n = 0; n < 4; ++n) fB[n] = lds_read128(lds0 + offB[n]);
    #pragma unroll
    for (int m = 0; m < 8; ++m) fA[m] = lds_read128(lds0 + offA[m]);

    auto issue_reads = [&](const int t, s8v (&na)[8], s8v (&nb)[4]) {
        const unsigned nbase = lds0 + (unsigned)((t + 1) & 3) * 32768u;
        #pragma unroll
        for (int n = 0; n < 4; ++n) nb[n] = lds_read128(nbase + offB[n]);
        #pragma unroll
        for (int m = 0; m < 8; ++m) na[m] = lds_read128(nbase + offA[m]);
    };
    auto do_mfma = [&](s8v (&ca)[8], s8v (&cb)[4]) {
        __builtin_amdgcn_s_setprio(1);
        #pragma unroll
        for (int m = 0; m < 8; ++m)
            #pragma unroll
            for (int n = 0; n < 4; ++n)
                acc[m][n] = __builtin_amdgcn_mfma_f32_16x16x32_bf16(ca[m], cb[n], acc[m][n], 0, 0, 0);
        __builtin_amdgcn_s_setprio(0);
    };
    auto tail_sync = [&](const int t) {
        if (t + 3 < NT)      asm volatile("s_waitcnt vmcnt(4)" ::: "memory");
        else if (t + 2 < NT) asm volatile("s_waitcnt vmcnt(0)" ::: "memory");
        __builtin_amdgcn_s_barrier();
    };

    auto bodyA = [&](const int t, s8v (&ca)[8], s8v (&cb)[4],
                     s8v (&na)[8], s8v (&nb)[4], const bool reads) {
        if (t + 3 < NT) { stageA(t + 3); stageB(t + 3); }
        if (reads) {
            issue_reads(t, na, nb);
            asm volatile("s_waitcnt lgkmcnt(12)" ::: "memory");
        } else {
            asm volatile("s_waitcnt lgkmcnt(0)" ::: "memory");
        }
        __builtin_amdgcn_sched_barrier(0);
        do_mfma(ca, cb);
        __builtin_amdgcn_sched_barrier(0);
        tail_sync(t);
    };
    auto bodyB = [&](const int t, s8v (&ca)[8], s8v (&cb)[4],
                     s8v (&na)[8], s8v (&nb)[4], const bool reads) {
        if (t + 3 < NT) { stageA(t + 3); stageB(t + 3); }
        asm volatile("s_waitcnt lgkmcnt(0)" ::: "memory");
        __builtin_amdgcn_sched_barrier(0);
        do_mfma(ca, cb);
        __builtin_amdgcn_sched_barrier(0);
        if (reads) issue_reads(t, na, nb);
        tail_sync(t);
    };

    if (wid < 4) {
        for (int tt = 0; tt < NT; tt += 2) {
            bodyA(tt,     fA, fB, gA, gB, true);
            bodyA(tt + 1, gA, gB, fA, fB, tt + 2 < NT);
        }
    } else {
        for (int tt = 0; tt < NT; tt += 2) {
            bodyB(tt,     fA, fB, gA, gB, true);
            bodyB(tt + 1, gA, gB, fA, fB, tt + 2 < NT);
        }
    }

    float* Ob = Out + (size_t)b * sO + (size_t)(mt * 256 + wm * 128) * ldO + nt * 256 + wn * 64;
    const int cr = (lane >> 4) << 2;
    const int cc = lane & 15;
    #pragma unroll
    for (int m = 0; m < 8; ++m)
        #pragma unroll
        for (int n = 0; n < 4; ++n)
            #pragma unroll
            for (int r = 0; r < 4; ++r)
                Ob[(size_t)(m * 16 + cr + r) * ldO + n * 16 + cc] = acc[m][n][r];
}

// ---------------- softmax (fp32 in-place + bf16 copy) ----------------
__global__ __launch_bounds__(256)
void softmax_rows_bf(float* __restrict__ P, unsigned short* __restrict__ Pb)
{
    float* p = P + (size_t)blockIdx.x * 2048;
    unsigned short* pb = Pb + (size_t)blockIdx.x * 2048;
    const int tid = threadIdx.x;

    float4 v0 = *reinterpret_cast<const float4*>(&p[tid * 4]);
    float4 v1 = *reinterpret_cast<const float4*>(&p[1024 + tid * 4]);

    float m = fmaxf(fmaxf(fmaxf(v0.x, v0.y), fmaxf(v0.z, v0.w)),
                    fmaxf(fmaxf(v1.x, v1.y), fmaxf(v1.z, v1.w)));
    #pragma unroll
    for (int off = 32; off; off >>= 1) m = fmaxf(m, __shfl_xor(m, off));

    __shared__ float red[8];
    const int wid = tid >> 6;
    if ((tid & 63) == 0) red[wid] = m;
    __syncthreads();
    m = fmaxf(fmaxf(red[0], red[1]), fmaxf(red[2], red[3]));

    v0.x = __expf(v0.x - m); v0.y = __expf(v0.y - m);
    v0.z = __expf(v0.z - m); v0.w = __expf(v0.w - m);
    v1.x = __expf(v1.x - m); v1.y = __expf(v1.y - m);
    v1.z = __expf(v1.z - m); v1.w = __expf(v1.w - m);

    float s = ((v0.x + v0.y) + (v0.z + v0.w)) + ((v1.x + v1.y) + (v1.z + v1.w));
    #pragma unroll
    for (int off = 32; off; off >>= 1) s += __shfl_xor(s, off);
    if ((tid & 63) == 0) red[4 + wid] = s;
    __syncthreads();
    const float inv = 1.0f / ((red[4] + red[5]) + (red[6] + red[7]));

    v0.x *= inv; v0.y *= inv; v0.z *= inv; v0.w *= inv;
    v1.x *= inv; v1.y *= inv; v1.z *= inv; v1.w *= inv;
    *reinterpret_cast<float4*>(&p[tid * 4]) = v0;
    *reinterpret_cast<float4*>(&p[1024 + tid * 4]) = v1;

    us4 h0, h1;
    h0.x = f2bf(v0.x); h0.y = f2bf(v0.y); h0.z = f2bf(v0.z); h0.w = f2bf(v0.w);
    h1.x = f2bf(v1.x); h1.y = f2bf(v1.y); h1.z = f2bf(v1.z); h1.w = f2bf(v1.w);
    *reinterpret_cast<us4*>(&pb[tid * 4]) = h0;
    *reinterpret_cast<us4*>(&pb[1024 + tid * 4]) = h1;
}

// ======================= fp32 fallback path =======================
#define BM 128
#define BN 128
#define BK 32
#define LDT 132

template <bool TRANSB>
__global__ __launch_bounds__(256, 2)
void gemm_tile(const float* __restrict__ X, const float* __restrict__ Y,
               float* __restrict__ Out,
               int ldX, int ldY, int ldO, int KD,
               long long strideX, long long strideY, long long strideO)
{
    __shared__ float As[BK][LDT];
    __shared__ float Bs[BK][LDT];
    const int b  = blockIdx.z;
    const int mt = blockIdx.y;
    const int nt = blockIdx.x;
    const float* Xb = X + (size_t)b * strideX + (size_t)mt * BM * ldX;
    const float* Yb = TRANSB ? (Y + (size_t)b * strideY + (size_t)nt * BN * ldY)
                             : (Y + (size_t)b * strideY + (size_t)nt * BN);
    float* Ob = Out + (size_t)b * strideO + (size_t)mt * BM * ldO + (size_t)nt * BN;
    const int tid = threadIdx.x;
    const int tx = tid & 15;
    const int ty = tid >> 4;
    const int sr = tid >> 3;
    const int sc = (tid & 7) << 2;
    const int br = tid >> 5;
    const int bc = (tid & 31) << 2;
    float acc[8][8];
    #pragma unroll
    for (int i = 0; i < 8; ++i)
        #pragma unroll
        for (int j = 0; j < 8; ++j) acc[i][j] = 0.f;
    for (int k0 = 0; k0 < KD; k0 += BK) {
        #pragma unroll
        for (int p = 0; p < 4; ++p) {
            const float4 v = *reinterpret_cast<const float4*>(
                &Xb[(size_t)(sr + 32 * p) * ldX + k0 + sc]);
            As[sc + 0][sr + 32 * p] = v.x;
            As[sc + 1][sr + 32 * p] = v.y;
            As[sc + 2][sr + 32 * p] = v.z;
            As[sc + 3][sr + 32 * p] = v.w;
        }
        if (TRANSB) {
            #pragma unroll
            for (int p = 0; p < 4; ++p) {
                const float4 v = *reinterpret_cast<const float4*>(
                    &Yb[(size_t)(sr + 32 * p) * ldY + k0 + sc]);
                Bs[sc + 0][sr + 32 * p] = v.x;
                Bs[sc + 1][sr + 32 * p] = v.y;
                Bs[sc + 2][sr + 32 * p] = v.z;
                Bs[sc + 3][sr + 32 * p] = v.w;
            }
        } else {
            #pragma unroll
            for (int p = 0; p < 4; ++p) {
                const float4 v = *reinterpret_cast<const float4*>(
                    &Yb[(size_t)(k0 + br + 8 * p) * ldY + bc]);
                *reinterpret_cast<float4*>(&Bs[br + 8 * p][bc]) = v;
            }
        }
        __syncthreads();
        #pragma unroll 8
        for (int kk = 0; kk < BK; ++kk) {
            const float4 a0 = *reinterpret_cast<const float4*>(&As[kk][ty * 4]);
            const float4 a1 = *reinterpret_cast<const float4*>(&As[kk][64 + ty * 4]);
            const float4 b0 = *reinterpret_cast<const float4*>(&Bs[kk][tx * 4]);
            const float4 b1 = *reinterpret_cast<const float4*>(&Bs[kk][64 + tx * 4]);
            const float av[8] = {a0.x, a0.y, a0.z, a0.w, a1.x, a1.y, a1.z, a1.w};
            const float bv[8] = {b0.x, b0.y, b0.z, b0.w, b1.x, b1.y, b1.z, b1.w};
            #pragma unroll
            for (int i = 0; i < 8; ++i)
                #pragma unroll
                for (int j = 0; j < 8; ++j)
                    acc[i][j] = fmaf(av[i], bv[j], acc[i][j]);
        }
        __syncthreads();
    }
    #pragma unroll
    for (int i = 0; i < 8; ++i) {
        const int r = (i < 4) ? (ty * 4 + i) : (64 + ty * 4 + (i - 4));
        const float4 w0 = make_float4(acc[i][0], acc[i][1], acc[i][2], acc[i][3]);
        const float4 w1 = make_float4(acc[i][4], acc[i][5], acc[i][6], acc[i][7]);
        *reinterpret_cast<float4*>(&Ob[(size_t)r * ldO + tx * 4])      = w0;
        *reinterpret_cast<float4*>(&Ob[(size_t)r * ldO + 64 + tx * 4]) = w1;
    }
}

__global__ __launch_bounds__(256)
void softmax_rows(float* __restrict__ P)
{
    float* p = P + (size_t)blockIdx.x * 2048;
    const int tid = threadIdx.x;
    float4 v0 = *reinterpret_cast<const float4*>(&p[tid * 4]);
    float4 v1 = *reinterpret_cast<const float4*>(&p[1024 + tid * 4]);
    float m = fmaxf(fmaxf(fmaxf(v0.x, v0.y), fmaxf(v0.z, v0.w)),
                    fmaxf(fmaxf(v1.x, v1.y), fmaxf(v1.z, v1.w)));
    #pragma unroll
    for (int off = 32; off; off >>= 1) m = fmaxf(m, __shfl_xor(m, off));
    __shared__ float red[8];
    const int wid = tid >> 6;
    if ((tid & 63) == 0) red[wid] = m;
    __syncthreads();
    m = fmaxf(fmaxf(red[0], red[1]), fmaxf(red[2], red[3]));
    v0.x = __expf(v0.x - m); v0.y = __expf(v0.y - m);
    v0.z = __expf(v0.z - m); v0.w = __expf(v0.w - m);
    v1.x = __expf(v1.x - m); v1.y = __expf(v1.y - m);
    v1.z = __expf(v1.z - m); v1.w = __expf(v1.w - m);
    float s = ((v0.x + v0.y) + (v0.z + v0.w)) + ((v1.x + v1.y) + (v1.z + v1.w));
    #pragma unroll
    for (int off = 32; off; off >>= 1) s += __shfl_xor(s, off);
    if ((tid & 63) == 0) red[4 + wid] = s;
    __syncthreads();
    const float inv = 1.0f / ((red[4] + red[5]) + (red[6] + red[7]));
    v0.x *= inv; v0.y *= inv; v0.z *= inv; v0.w *= inv;
    v1.x *= inv; v1.y *= inv; v1.z *= inv; v1.w *= inv;
    *reinterpret_cast<float4*>(&p[tid * 4]) = v0;
    *reinterpret_cast<float4*>(&p[1024 + tid * 4]) = v1;
}

// =========================== launcher ===========================
extern "C" void kernel_launch(void* const* d_in, const int* in_sizes, int n_in,
                              void* d_out, int out_size, void* d_ws, size_t ws_size,
                              hipStream_t stream)
{
    const float* dec = (const float*)d_in[0];   // [16,1024,1024]
    const float* enc = (const float*)d_in[1];   // [16,2048,1024]
    float* ctx  = (float*)d_out;                        // [16,1024,1024]
    float* attn = ctx + (size_t)16 * 1024 * 1024;       // [16,1024,2048]

    const long long DECN = 16LL * 1024 * 1024;
    const long long ENCN = 16LL * 2048 * 1024;
    const size_t NEED = (size_t)(2 * DECN + 4 * ENCN) * 2;  // 320 MB

    if (ws_size >= NEED) {
        unsigned short* decH  = (unsigned short*)d_ws;
        unsigned short* decL  = decH + DECN;
        unsigned short* encH  = decL + DECN;
        unsigned short* encL  = encH + ENCN;
        unsigned short* encT  = encL + ENCN;   // [16][1024][2048]
        unsigned short* attnB = encT + ENCN;   // [16][1024][2048]

        hipFuncSetAttribute((const void*)&gemm1_quad<32, 8, 4>,
                            hipFuncAttributeMaxDynamicSharedMemorySize, 131072);
        hipFuncSetAttribute((const void*)&gemm_nt_256<1, 2048, 4, 4>,
                            hipFuncAttributeMaxDynamicSharedMemorySize, 131072);

        split_convert<<<2048, 256, 0, stream>>>(dec, decH, decL, (int)(DECN / 4));
        split_convert_enc<<<dim3(32, 16, 16), 256, 0, stream>>>(enc, encH, encL, encT);

        // scores = dec @ enc^T: quad-set {hh + hl + lh}, K = 1024
        gemm1_quad<32, 8, 4><<<dim3(8, 4, 16), 512, 131072, stream>>>(
            decH, decL, encH, encL, attn,
            1024, 1024, 2048,
            1024LL * 1024, 2048LL * 1024, 1024LL * 2048);

        softmax_rows_bf<<<16 * 1024, 256, 0, stream>>>(attn, attnB);

        // context = attnB (NT) encT, K = 2048
        gemm_nt_256<1, 2048, 4, 4><<<dim3(4, 4, 16), 512, 131072, stream>>>(
            attnB, attnB, attnB, encT, encT, encT, ctx,
            2048, 2048, 1024,
            1024LL * 2048, 1024LL * 2048, 1024LL * 1024);
    } else {
        gemm_tile<true><<<dim3(2048 / BN, 1024 / BM, 16), 256, 0, stream>>>(
            dec, enc, attn, 1024, 1024, 2048, 1024,
            1024LL * 1024, 2048LL * 1024, 1024LL * 2048);
        softmax_rows<<<dim3(16 * 1024), 256, 0, stream>>>(attn);
        gemm_tile<false><<<dim3(1024 / BN, 1024 / BM, 16), 256, 0, stream>>>(
            attn, enc, ctx, 2048, 1024, 1024, 2048,
            1024LL * 2048, 2048LL * 1024, 1024LL * 1024);
    }
}